// Round 1
// baseline (1308.920 us; speedup 1.0000x reference)
//
#include <hip/hip_runtime.h>
#include <hip/hip_bf16.h>

// Problem constants (match reference)
#define MM 12288
#define NCH 8      // B * C_IN
#define COUT 16
#define KK 5
#define ROWS 4     // output rows per wave

// One wave (64 threads) per block. Each wave computes ROWS consecutive output
// rows of vout = L @ vin for all 8 channels. Lanes split the j (column)
// dimension with float4 loads => fully coalesced streaming of L (HBM-bound).
// vin is [NCH][MM] (each channel contiguous) and stays L2-resident (384 KB).
__global__ __launch_bounds__(64) void matpanel_kernel(
        const float* __restrict__ L,
        const float* __restrict__ vin,   // [NCH][MM]
        float* __restrict__ vout) {      // [NCH][MM]
    const int lane = threadIdx.x;            // 0..63
    const int row0 = blockIdx.x * ROWS;

    float acc[ROWS][NCH];
#pragma unroll
    for (int r = 0; r < ROWS; ++r)
#pragma unroll
        for (int c = 0; c < NCH; ++c) acc[r][c] = 0.f;

    // 48 iterations: 64 lanes * 4 floats = 256 columns per iteration
    for (int it = 0; it < MM / 256; ++it) {
        const int j = it * 256 + lane * 4;
        float4 v[NCH];
#pragma unroll
        for (int c = 0; c < NCH; ++c)
            v[c] = *(const float4*)(vin + (size_t)c * MM + j);
#pragma unroll
        for (int r = 0; r < ROWS; ++r) {
            const float4 a = *(const float4*)(L + (size_t)(row0 + r) * MM + j);
#pragma unroll
            for (int c = 0; c < NCH; ++c) {
                acc[r][c] += a.x * v[c].x + a.y * v[c].y
                           + a.z * v[c].z + a.w * v[c].w;
            }
        }
    }

    // Cross-lane reduction: 32 values (r*8+c) distributed one-per-lane.
    float val[ROWS * NCH];
#pragma unroll
    for (int r = 0; r < ROWS; ++r)
#pragma unroll
        for (int c = 0; c < NCH; ++c) val[r * NCH + c] = acc[r][c];

    // Fold upper 32 lanes onto lower 32 (both halves end with pair sums).
#pragma unroll
    for (int v = 0; v < 32; ++v) val[v] += __shfl_xor(val[v], 32, 64);

    // Butterfly: value-index bit d <-> lane bit d.
#pragma unroll
    for (int d = 16; d >= 1; d >>= 1) {
        const bool up = (lane & d) != 0;
#pragma unroll
        for (int v = 0; v < 16; ++v) {
            if (v < d) {
                const float keep = up ? val[v + d] : val[v];
                const float send = up ? val[v] : val[v + d];
                const float recv = __shfl_xor(send, d, 64);
                val[v] = keep + recv;
            }
        }
    }

    // Lane l (l < 32) holds the full sum for value index l: r = l>>3, c = l&7.
    if (lane < 32) {
        const int r = lane >> 3;
        const int c = lane & 7;
        vout[(size_t)c * MM + row0 + r] = val[0];
    }
}

// y[o][m] = bias[o] + sum_{c,k} theta[o][c][k] * P_k[c][m],  P_0 = x
__global__ __launch_bounds__(256) void combine_kernel(
        const float* __restrict__ x,      // [NCH][MM]  (power 0)
        const float* __restrict__ P,      // [KK-1][NCH][MM] (powers 1..4)
        const float* __restrict__ theta,  // [COUT][NCH][KK]
        const float* __restrict__ bias,   // [COUT]
        float* __restrict__ y) {          // [COUT][MM]
    const int m = blockIdx.x * blockDim.x + threadIdx.x;
    if (m >= MM) return;

    float p[KK][NCH];
#pragma unroll
    for (int c = 0; c < NCH; ++c) p[0][c] = x[(size_t)c * MM + m];
#pragma unroll
    for (int k = 1; k < KK; ++k)
#pragma unroll
        for (int c = 0; c < NCH; ++c)
            p[k][c] = P[((size_t)(k - 1) * NCH + c) * MM + m];

#pragma unroll
    for (int o = 0; o < COUT; ++o) {
        float acc = bias[o];
#pragma unroll
        for (int c = 0; c < NCH; ++c)
#pragma unroll
            for (int k = 0; k < KK; ++k)
                acc += theta[(o * NCH + c) * KK + k] * p[k][c];
        y[(size_t)o * MM + m] = acc;
    }
}

extern "C" void kernel_launch(void* const* d_in, const int* in_sizes, int n_in,
                              void* d_out, int out_size, void* d_ws, size_t ws_size,
                              hipStream_t stream) {
    const float* L     = (const float*)d_in[0];  // [MM][MM]
    const float* x     = (const float*)d_in[1];  // [1][NCH][MM]
    const float* theta = (const float*)d_in[2];  // [COUT][NCH][KK]
    const float* bias  = (const float*)d_in[3];  // [1][COUT][1]
    float* out = (float*)d_out;                  // [1][COUT][MM]
    float* P   = (float*)d_ws;                   // 4 * NCH * MM floats = 1.57 MB

    const size_t S = (size_t)NCH * MM;
    const int grid = MM / ROWS;  // 3072 blocks of 64 threads = 12 waves/CU

    matpanel_kernel<<<grid, 64, 0, stream>>>(L, x,         P);
    matpanel_kernel<<<grid, 64, 0, stream>>>(L, P,         P + S);
    matpanel_kernel<<<grid, 64, 0, stream>>>(L, P + S,     P + 2 * S);
    matpanel_kernel<<<grid, 64, 0, stream>>>(L, P + 2 * S, P + 3 * S);

    combine_kernel<<<(MM + 255) / 256, 256, 0, stream>>>(x, P, theta, bias, out);
}